// Round 4
// baseline (349.968 us; speedup 1.0000x reference)
//
#include <hip/hip_runtime.h>

// LSTMNet: 3-layer LSTM (H=6, in=1), B=8192, T=512, FC to 1.
// R4: R3 + amdgpu_waves_per_eu(2,2).
// R3 post-mortem: WRITE_SIZE=32MB == 60 floats x 4B x 64 lanes x 2048 waves ->
// the register allocator SPILLED the pinned weight set to scratch (VGPR=56,
// targeting ~9 waves/EU occupancy the 512-block grid can never reach) and
// reloaded it every timestep (FETCH 8.2GB = L2 leakage of 16TB scratch reads).
// Fix: clamp waves/EU to exactly 2 -> 256-VGPR budget -> ~115-reg working set
// (68 weights + 30 state + temps) stays resident, zero scratch traffic.
// Layout: sub=lane&15; p=sub>>3 gate pair (p0: i,f | p1: g,o); j=unit 0..5
// (subs 6,7 duplicate 0,1). Weights pre-scaled by -log2e (sigmoid rows) or
// +2log2e (tanh row) so activation = fma(A, rcp(1+exp2(z)), B).

#define SEQT 512

__device__ __forceinline__ float fexp2(float x) { return __builtin_amdgcn_exp2f(x); }
__device__ __forceinline__ float frcp(float x)  { return __builtin_amdgcn_rcpf(x); }

// Force value into a VGPR; opaque to the optimizer (prevents load remat/sink).
#define PIN(v) asm volatile("" : "+v"(v))

template <int OFF>
__device__ __forceinline__ float swz(float v) {
    return __int_as_float(__builtin_amdgcn_ds_swizzle(__float_as_int(v), OFF));
}

__device__ __forceinline__ float act(float z, float A, float B) {
    float r = frcp(1.0f + fexp2(z));
    return fmaf(A, r, B);
}
__device__ __forceinline__ float tanh_c(float c) {
    return 1.0f - 2.0f * frcp(1.0f + fexp2(2.8853900817779268f * c));
}

// broadcast from lane (lane&0x10)|k within 16-lane group (swizzle BitMode)
#define BCAST6(dst, src)              \
    dst[0] = swz<0x010>(src);         \
    dst[1] = swz<0x030>(src);         \
    dst[2] = swz<0x050>(src);         \
    dst[3] = swz<0x070>(src);         \
    dst[4] = swz<0x090>(src);         \
    dst[5] = swz<0x0B0>(src);

#define XCHG 0x201F  // xor=8: partner lane (p0<->p1) within 16-group

__global__ __launch_bounds__(256)
__attribute__((amdgpu_waves_per_eu(2, 2)))
void lstm3_kernel(
    const float* __restrict__ x,
    const float* __restrict__ Wih0, const float* __restrict__ Whh0,
    const float* __restrict__ bih0, const float* __restrict__ bhh0,
    const float* __restrict__ Wih1, const float* __restrict__ Whh1,
    const float* __restrict__ bih1, const float* __restrict__ bhh1,
    const float* __restrict__ Wih2, const float* __restrict__ Whh2,
    const float* __restrict__ bih2, const float* __restrict__ bhh2,
    const float* __restrict__ fcw, const float* __restrict__ fcb,
    float* __restrict__ out)
{
    const int tid  = blockIdx.x * blockDim.x + threadIdx.x;
    const int lane = threadIdx.x & 63;
    const int sub  = lane & 15;
    const int p    = sub >> 3;                // 0: gates i,f   1: gates g,o
    const int jj   = sub & 7;
    const int j    = (jj < 6) ? jj : jj - 6;  // unit (subs 6,7 duplicate 0,1)
    const int b    = tid >> 4;                // batch element

    const float L2E = 1.4426950408889634f;
    const float s0  = p ? 2.0f * L2E : -L2E;  // first row of pair (i or g)
    const float s1  = -L2E;                   // second row (f or o): sigmoid
    const float A0  = p ? -2.0f : 1.0f;
    const float B0  = p ? 1.0f : 0.0f;

    const int g0 = 2 * p, g1 = 2 * p + 1;
    const int r0 = 6 * g0 + j, r1 = 6 * g1 + j;

    // ---- load + pre-scale weights, then PIN each into a VGPR ----
    float wx0 = Wih0[r0] * s0, wx1 = Wih0[r1] * s1;
    float b00 = (bih0[r0] + bhh0[r0]) * s0, b01 = (bih0[r1] + bhh0[r1]) * s1;
    float b10 = (bih1[r0] + bhh1[r0]) * s0, b11 = (bih1[r1] + bhh1[r1]) * s1;
    float b20 = (bih2[r0] + bhh2[r0]) * s0, b21 = (bih2[r1] + bhh2[r1]) * s1;
    PIN(wx0); PIN(wx1); PIN(b00); PIN(b01);
    PIN(b10); PIN(b11); PIN(b20); PIN(b21);

    float whh0a[6], whh0b[6];
    float wih1a[6], wih1b[6], whh1a[6], whh1b[6];
    float wih2a[6], wih2b[6], whh2a[6], whh2b[6];
#pragma unroll
    for (int k = 0; k < 6; ++k) {
        whh0a[k] = Whh0[r0 * 6 + k] * s0;  whh0b[k] = Whh0[r1 * 6 + k] * s1;
        wih1a[k] = Wih1[r0 * 6 + k] * s0;  wih1b[k] = Wih1[r1 * 6 + k] * s1;
        whh1a[k] = Whh1[r0 * 6 + k] * s0;  whh1b[k] = Whh1[r1 * 6 + k] * s1;
        wih2a[k] = Wih2[r0 * 6 + k] * s0;  wih2b[k] = Wih2[r1 * 6 + k] * s1;
        whh2a[k] = Whh2[r0 * 6 + k] * s0;  whh2b[k] = Whh2[r1 * 6 + k] * s1;
        PIN(whh0a[k]); PIN(whh0b[k]);
        PIN(wih1a[k]); PIN(wih1b[k]);
        PIN(whh1a[k]); PIN(whh1b[k]);
        PIN(wih2a[k]); PIN(wih2b[k]);
        PIN(whh2a[k]); PIN(whh2b[k]);
    }

    float h0a[6] = {0, 0, 0, 0, 0, 0};
    float h1a[6] = {0, 0, 0, 0, 0, 0};
    float h2a[6] = {0, 0, 0, 0, 0, 0};
    float c0 = 0.f, c1 = 0.f, c2 = 0.f;

    const float4* xq = (const float4*)(x + (size_t)b * SEQT);

    float4 q = xq[0];  // all 16 lanes of the group load the same 16B

    for (int t4 = 0; t4 < SEQT / 4; ++t4) {
        float4 qn;
        if (t4 + 1 < SEQT / 4) qn = xq[t4 + 1];  // prefetch next quad

        float xts[4] = {q.x, q.y, q.z, q.w};
#pragma unroll
        for (int s = 0; s < 4; ++s) {
            const float xt = xts[s];

            // ---- recurrent dots for ALL layers first (independent ILP) ----
            float z00 = fmaf(wx0, xt, b00), z01 = fmaf(wx1, xt, b01);
            float z10 = b10, z11 = b11, z20 = b20, z21 = b21;
#pragma unroll
            for (int k = 0; k < 6; ++k) {
                z00 = fmaf(whh0a[k], h0a[k], z00);
                z01 = fmaf(whh0b[k], h0a[k], z01);
            }
#pragma unroll
            for (int k = 0; k < 6; ++k) {
                z10 = fmaf(whh1a[k], h1a[k], z10);
                z11 = fmaf(whh1b[k], h1a[k], z11);
            }
#pragma unroll
            for (int k = 0; k < 6; ++k) {
                z20 = fmaf(whh2a[k], h2a[k], z20);
                z21 = fmaf(whh2b[k], h2a[k], z21);
            }

            // ---------------- layer 0 ----------------
            {
                float a0 = act(z00, A0, B0);      // p0: i   p1: g
                float a1 = act(z01, 1.0f, 0.0f);  // p0: f   p1: o
                float gx = swz<XCHG>(a0);
                float ox = swz<XCHG>(a1);
                c0 = fmaf(a1, c0, a0 * gx);       // valid on p0 lanes
                float h = ox * tanh_c(c0);
                BCAST6(h0a, h);                   // reads p0 lanes 0..5
            }

            // ---------------- layer 1 ----------------
#pragma unroll
            for (int k = 0; k < 6; ++k) {
                z10 = fmaf(wih1a[k], h0a[k], z10);
                z11 = fmaf(wih1b[k], h0a[k], z11);
            }
            {
                float a0 = act(z10, A0, B0);
                float a1 = act(z11, 1.0f, 0.0f);
                float gx = swz<XCHG>(a0);
                float ox = swz<XCHG>(a1);
                c1 = fmaf(a1, c1, a0 * gx);
                float h = ox * tanh_c(c1);
                BCAST6(h1a, h);
            }

            // ---------------- layer 2 ----------------
#pragma unroll
            for (int k = 0; k < 6; ++k) {
                z20 = fmaf(wih2a[k], h1a[k], z20);
                z21 = fmaf(wih2b[k], h1a[k], z21);
            }
            {
                float a0 = act(z20, A0, B0);
                float a1 = act(z21, 1.0f, 0.0f);
                float gx = swz<XCHG>(a0);
                float ox = swz<XCHG>(a1);
                c2 = fmaf(a1, c2, a0 * gx);
                float h = ox * tanh_c(c2);
                BCAST6(h2a, h);
            }
        }
        q = qn;
    }

    // ---- final FC ----
    if (sub == 0) {
        float o = fcb[0];
#pragma unroll
        for (int k = 0; k < 6; ++k)
            o = fmaf(fcw[k], h2a[k], o);
        out[b] = o;
    }
}

extern "C" void kernel_launch(void* const* d_in, const int* in_sizes, int n_in,
                              void* d_out, int out_size, void* d_ws, size_t ws_size,
                              hipStream_t stream) {
    const float* x    = (const float*)d_in[0];
    const float* Wih0 = (const float*)d_in[1];
    const float* Whh0 = (const float*)d_in[2];
    const float* bih0 = (const float*)d_in[3];
    const float* bhh0 = (const float*)d_in[4];
    const float* Wih1 = (const float*)d_in[5];
    const float* Whh1 = (const float*)d_in[6];
    const float* bih1 = (const float*)d_in[7];
    const float* bhh1 = (const float*)d_in[8];
    const float* Wih2 = (const float*)d_in[9];
    const float* Whh2 = (const float*)d_in[10];
    const float* bih2 = (const float*)d_in[11];
    const float* bhh2 = (const float*)d_in[12];
    const float* fcw  = (const float*)d_in[13];
    const float* fcb  = (const float*)d_in[14];
    float* out = (float*)d_out;

    const int B = out_size;            // 8192
    const int threads = B * 16;        // 16 lanes per batch element
    const int block = 256;
    const int grid = threads / block;  // 512 blocks -> 2 waves/SIMD
    lstm3_kernel<<<grid, block, 0, stream>>>(
        x, Wih0, Whh0, bih0, bhh0, Wih1, Whh1, bih1, bhh1,
        Wih2, Whh2, bih2, bhh2, fcw, fcb, out);
}

// Round 5
// 346.402 us; speedup vs baseline: 1.0103x; 1.0103x over previous
//
#include <hip/hip_runtime.h>

// LSTMNet: 3-layer LSTM (H=6, in=1), B=8192, T=512, FC to 1.
// R5: kill ALL local arrays.
// Evidence across R1-R4: WRITE_SIZE == 32MB == one store per weight float per
// thread, FETCH ~8.2GB, regardless of PIN / waves_per_eu. Diagnosis: the
// float[6] weight arrays never get promoted out of scratch (early SROA runs
// pre-unroll with variable index; late AMDGPUPromoteAlloca has an occupancy
// byte budget that 240B/thread exceeds; R3/R4's asm on elements blocks it
// entirely). Every weight use was a scratch reload -> ~60 VMEM ops +
// vmcnt stalls per lane-timestep.
// Fix: all weights/state as named scalars (SSA by construction), no PIN,
// waves_per_eu(2,2) keeps the 256-VGPR RA budget. Structure otherwise = R4:
// 16 lanes/elem, gate-pair split (p0: i,f | p1: g,o), swizzle exchange,
// weights pre-scaled by -log2e (sigmoid) / +2log2e (tanh) so
// activation = fma(A, rcp(1+exp2(z)), B).

#define SEQT 512

__device__ __forceinline__ float fexp2(float x) { return __builtin_amdgcn_exp2f(x); }
__device__ __forceinline__ float frcp(float x)  { return __builtin_amdgcn_rcpf(x); }

template <int OFF>
__device__ __forceinline__ float swz(float v) {
    return __int_as_float(__builtin_amdgcn_ds_swizzle(__float_as_int(v), OFF));
}

__device__ __forceinline__ float act(float z, float A, float B) {
    return fmaf(A, frcp(1.0f + fexp2(z)), B);
}
__device__ __forceinline__ float tanh_c(float c) {
    return 1.0f - 2.0f * frcp(1.0f + fexp2(2.8853900817779268f * c));
}

// --- scalar 6-vectors via macro-generated names (NO allocas anywhere) ---
#define DECL6(n)  float n##0, n##1, n##2, n##3, n##4, n##5
#define LOAD6(n, P, row, sc)                                   \
    {                                                          \
        const float* _p = (P) + (row) * 6;                     \
        n##0 = _p[0] * (sc); n##1 = _p[1] * (sc);              \
        n##2 = _p[2] * (sc); n##3 = _p[3] * (sc);              \
        n##4 = _p[4] * (sc); n##5 = _p[5] * (sc);              \
    }
#define ZERO6(n)  n##0 = n##1 = n##2 = n##3 = n##4 = n##5 = 0.0f
#define DOT6(z, w, h)                                          \
    z = fmaf(w##0, h##0, z); z = fmaf(w##1, h##1, z);          \
    z = fmaf(w##2, h##2, z); z = fmaf(w##3, h##3, z);          \
    z = fmaf(w##4, h##4, z); z = fmaf(w##5, h##5, z)
// broadcast h from lane (lane&0x10)|k within 16-lane group (swizzle BitMode)
#define BCAST6(n, src)                                         \
    n##0 = swz<0x010>(src); n##1 = swz<0x030>(src);            \
    n##2 = swz<0x050>(src); n##3 = swz<0x070>(src);            \
    n##4 = swz<0x090>(src); n##5 = swz<0x0B0>(src)

#define XCHG 0x201F  // xor=8: partner lane (p0<->p1) within 16-group

__global__ __launch_bounds__(256)
__attribute__((amdgpu_waves_per_eu(2, 2)))
void lstm3_kernel(
    const float* __restrict__ x,
    const float* __restrict__ Wih0, const float* __restrict__ Whh0,
    const float* __restrict__ bih0, const float* __restrict__ bhh0,
    const float* __restrict__ Wih1, const float* __restrict__ Whh1,
    const float* __restrict__ bih1, const float* __restrict__ bhh1,
    const float* __restrict__ Wih2, const float* __restrict__ Whh2,
    const float* __restrict__ bih2, const float* __restrict__ bhh2,
    const float* __restrict__ fcw, const float* __restrict__ fcb,
    float* __restrict__ out)
{
    const int tid  = blockIdx.x * blockDim.x + threadIdx.x;
    const int lane = threadIdx.x & 63;
    const int sub  = lane & 15;
    const int p    = sub >> 3;                // 0: gates i,f   1: gates g,o
    const int jj   = sub & 7;
    const int j    = (jj < 6) ? jj : jj - 6;  // unit (subs 6,7 duplicate 0,1)
    const int b    = tid >> 4;                // batch element

    const float L2E = 1.4426950408889634f;
    const float s0  = p ? 2.0f * L2E : -L2E;  // first row of pair (i or g)
    const float s1  = -L2E;                   // second row (f or o): sigmoid
    const float A0  = p ? -2.0f : 1.0f;
    const float B0  = p ? 1.0f : 0.0f;

    const int r0 = 6 * (2 * p) + j, r1 = 6 * (2 * p + 1) + j;

    // ---- weights as named scalars, pre-scaled ----
    float wx0 = Wih0[r0] * s0, wx1 = Wih0[r1] * s1;
    float b00 = (bih0[r0] + bhh0[r0]) * s0, b01 = (bih0[r1] + bhh0[r1]) * s1;
    float b10 = (bih1[r0] + bhh1[r0]) * s0, b11 = (bih1[r1] + bhh1[r1]) * s1;
    float b20 = (bih2[r0] + bhh2[r0]) * s0, b21 = (bih2[r1] + bhh2[r1]) * s1;

    DECL6(u0a); DECL6(u0b);                    // Whh0 rows r0, r1
    DECL6(v1a); DECL6(v1b); DECL6(u1a); DECL6(u1b);  // Wih1 / Whh1
    DECL6(v2a); DECL6(v2b); DECL6(u2a); DECL6(u2b);  // Wih2 / Whh2
    LOAD6(u0a, Whh0, r0, s0); LOAD6(u0b, Whh0, r1, s1);
    LOAD6(v1a, Wih1, r0, s0); LOAD6(v1b, Wih1, r1, s1);
    LOAD6(u1a, Whh1, r0, s0); LOAD6(u1b, Whh1, r1, s1);
    LOAD6(v2a, Wih2, r0, s0); LOAD6(v2b, Wih2, r1, s1);
    LOAD6(u2a, Whh2, r0, s0); LOAD6(u2b, Whh2, r1, s1);

    DECL6(h0); DECL6(h1); DECL6(h2);
    ZERO6(h0); ZERO6(h1); ZERO6(h2);
    float c0 = 0.f, c1 = 0.f, c2 = 0.f;

    const float4* xq = (const float4*)(x + (size_t)b * SEQT);
    float4 q = xq[0];  // all 16 lanes of the group load the same 16B

    for (int t4 = 0; t4 < SEQT / 4; ++t4) {
        float4 qn;
        if (t4 + 1 < SEQT / 4) qn = xq[t4 + 1];  // prefetch next quad

#pragma unroll
        for (int s = 0; s < 4; ++s) {
            const float xt = (s == 0) ? q.x : (s == 1) ? q.y : (s == 2) ? q.z : q.w;

            // ---- recurrent dots for ALL layers first (independent ILP) ----
            float z00 = fmaf(wx0, xt, b00), z01 = fmaf(wx1, xt, b01);
            float z10 = b10, z11 = b11, z20 = b20, z21 = b21;
            DOT6(z00, u0a, h0);  DOT6(z01, u0b, h0);
            DOT6(z10, u1a, h1);  DOT6(z11, u1b, h1);
            DOT6(z20, u2a, h2);  DOT6(z21, u2b, h2);

            // ---------------- layer 0 ----------------
            {
                float a0 = act(z00, A0, B0);      // p0: i   p1: g
                float a1 = act(z01, 1.0f, 0.0f);  // p0: f   p1: o
                float gx = swz<XCHG>(a0);
                float ox = swz<XCHG>(a1);
                c0 = fmaf(a1, c0, a0 * gx);       // valid on p0 lanes
                float h = ox * tanh_c(c0);
                BCAST6(h0, h);                    // reads p0 lanes 0..5
            }

            // ---------------- layer 1 ----------------
            DOT6(z10, v1a, h0);  DOT6(z11, v1b, h0);
            {
                float a0 = act(z10, A0, B0);
                float a1 = act(z11, 1.0f, 0.0f);
                float gx = swz<XCHG>(a0);
                float ox = swz<XCHG>(a1);
                c1 = fmaf(a1, c1, a0 * gx);
                float h = ox * tanh_c(c1);
                BCAST6(h1, h);
            }

            // ---------------- layer 2 ----------------
            DOT6(z20, v2a, h1);  DOT6(z21, v2b, h1);
            {
                float a0 = act(z20, A0, B0);
                float a1 = act(z21, 1.0f, 0.0f);
                float gx = swz<XCHG>(a0);
                float ox = swz<XCHG>(a1);
                c2 = fmaf(a1, c2, a0 * gx);
                float h = ox * tanh_c(c2);
                BCAST6(h2, h);
            }
        }
        q = qn;
    }

    // ---- final FC (h2 holds the broadcast final hidden state) ----
    if (sub == 0) {
        float o = fcb[0];
        o = fmaf(fcw[0], h20, o);
        o = fmaf(fcw[1], h21, o);
        o = fmaf(fcw[2], h22, o);
        o = fmaf(fcw[3], h23, o);
        o = fmaf(fcw[4], h24, o);
        o = fmaf(fcw[5], h25, o);
        out[b] = o;
    }
}

extern "C" void kernel_launch(void* const* d_in, const int* in_sizes, int n_in,
                              void* d_out, int out_size, void* d_ws, size_t ws_size,
                              hipStream_t stream) {
    const float* x    = (const float*)d_in[0];
    const float* Wih0 = (const float*)d_in[1];
    const float* Whh0 = (const float*)d_in[2];
    const float* bih0 = (const float*)d_in[3];
    const float* bhh0 = (const float*)d_in[4];
    const float* Wih1 = (const float*)d_in[5];
    const float* Whh1 = (const float*)d_in[6];
    const float* bih1 = (const float*)d_in[7];
    const float* bhh1 = (const float*)d_in[8];
    const float* Wih2 = (const float*)d_in[9];
    const float* Whh2 = (const float*)d_in[10];
    const float* bih2 = (const float*)d_in[11];
    const float* bhh2 = (const float*)d_in[12];
    const float* fcw  = (const float*)d_in[13];
    const float* fcb  = (const float*)d_in[14];
    float* out = (float*)d_out;

    const int B = out_size;            // 8192
    const int threads = B * 16;        // 16 lanes per batch element
    const int block = 256;
    const int grid = threads / block;  // 512 blocks -> 2 waves/SIMD
    lstm3_kernel<<<grid, block, 0, stream>>>(
        x, Wih0, Whh0, bih0, bhh0, Wih1, Whh1, bih1, bhh1,
        Wih2, Whh2, bih2, bhh2, fcw, fcb, out);
}

// Round 6
// 332.016 us; speedup vs baseline: 1.0541x; 1.0433x over previous
//
#include <hip/hip_runtime.h>

// LSTMNet: 3-layer LSTM (H=6, in=1), B=8192, T=512, FC to 1.
// R6: layer-skewed pipeline.
// R5 post-mortem: FETCH/WRITE are KB -> 8.3 MB / 32 KB. No spills ever
// (VGPR 88 = full working set). Kernel is latency-bound: the 3-layer
// serial chain (dots->act->XCHG->cell->tanh->BCAST, ~170cyc each) runs
// ~1370 cyc/SIMD-ts vs ~530 issue floor.
// Fix: superstep tau computes L0@tau, L1@(tau-1), L2@(tau-2); L1/L2 read
// the PREVIOUS superstep's h0/h1, so the three chains are independent
// (3-way ILP x 2 waves/SIMD). Gate split now (p0: i,g | p1: f,o): i*g
// forms locally on p0, ONE swizzle exchange, cell+tanh on p1, BCAST from
// p1 lanes. Sigmoid a0 needs no fma (act = rcp(1+exp2(z)), weights
// pre-scaled by -log2e; tanh rows by +2log2e with fma(-2,r,1)).
// 2 prologue + 2 epilogue supersteps peeled with compile-time flags.

#define SEQT 512

__device__ __forceinline__ float fexp2(float x) { return __builtin_amdgcn_exp2f(x); }
__device__ __forceinline__ float frcp(float x)  { return __builtin_amdgcn_rcpf(x); }

template <int OFF>
__device__ __forceinline__ float swz(float v) {
    return __int_as_float(__builtin_amdgcn_ds_swizzle(__float_as_int(v), OFF));
}

#define XCHG 0x201F  // BitMode xor=8: p0<->p1 partner within 16-lane group

// --- scalar 6-vectors (named scalars, no allocas) ---
#define DECL6(n)  float n##0, n##1, n##2, n##3, n##4, n##5
#define LOAD6(n, P, row, sc) { const float* _p = (P) + (row) * 6;        \
    n##0 = _p[0] * (sc); n##1 = _p[1] * (sc); n##2 = _p[2] * (sc);       \
    n##3 = _p[3] * (sc); n##4 = _p[4] * (sc); n##5 = _p[5] * (sc); }
#define ZERO6(n)  n##0 = n##1 = n##2 = n##3 = n##4 = n##5 = 0.0f
#define DOT6(z, w, h)                                                    \
    z = fmaf(w##0, h##0, z); z = fmaf(w##1, h##1, z);                    \
    z = fmaf(w##2, h##2, z); z = fmaf(w##3, h##3, z);                    \
    z = fmaf(w##4, h##4, z); z = fmaf(w##5, h##5, z)

// broadcast h from p1 lanes (sub 8+k) of each 16-lane group:
// offset = ((8+k)<<5) | and(0x10)
#define BCAST6(n, src)                                                   \
    n##0 = swz<0x110>(src); n##1 = swz<0x130>(src);                      \
    n##2 = swz<0x150>(src); n##3 = swz<0x170>(src);                      \
    n##4 = swz<0x190>(src); n##5 = swz<0x1B0>(src)

__device__ __forceinline__ float tanh_c(float c) {
    return fmaf(-2.0f, frcp(1.0f + fexp2(2.8853900817779268f * c)), 1.0f);
}

__global__ __launch_bounds__(256)
__attribute__((amdgpu_waves_per_eu(2, 2)))
void lstm3_kernel(
    const float* __restrict__ x,
    const float* __restrict__ Wih0, const float* __restrict__ Whh0,
    const float* __restrict__ bih0, const float* __restrict__ bhh0,
    const float* __restrict__ Wih1, const float* __restrict__ Whh1,
    const float* __restrict__ bih1, const float* __restrict__ bhh1,
    const float* __restrict__ Wih2, const float* __restrict__ Whh2,
    const float* __restrict__ bih2, const float* __restrict__ bhh2,
    const float* __restrict__ fcw, const float* __restrict__ fcb,
    float* __restrict__ out)
{
    const int tid  = blockIdx.x * blockDim.x + threadIdx.x;
    const int lane = threadIdx.x & 63;
    const int sub  = lane & 15;
    const int p    = sub >> 3;                // 0: gates i,g   1: gates f,o
    const int jj   = sub & 7;
    const int j    = (jj < 6) ? jj : jj - 6;  // unit (subs 6,7 duplicate 0,1)
    const int b    = tid >> 4;                // batch element

    const float L2E = 1.4426950408889634f;
    // z0 row: i (p0) or f (p1) -> both sigmoid, scale -log2e.
    // z1 row: g (p0, tanh, +2log2e) or o (p1, sigmoid, -log2e).
    const float s0 = -L2E;
    const float s1 = p ? -L2E : 2.0f * L2E;
    const float A1 = p ? 1.0f : -2.0f;        // a1 = fma(A1, rcp(1+exp2(z1)), B1)
    const float B1 = p ? 0.0f : 1.0f;

    // PyTorch row blocks: i[0..6), f[6..12), g[12..18), o[18..24)
    const int r0 = (p ? 6 : 0) + j;           // i or f
    const int r1 = (p ? 18 : 12) + j;         // o or g

    // ---- weights as named scalars, pre-scaled ----
    float wx0 = Wih0[r0] * s0, wx1 = Wih0[r1] * s1;
    float b00 = (bih0[r0] + bhh0[r0]) * s0, b01 = (bih0[r1] + bhh0[r1]) * s1;
    float b10 = (bih1[r0] + bhh1[r0]) * s0, b11 = (bih1[r1] + bhh1[r1]) * s1;
    float b20 = (bih2[r0] + bhh2[r0]) * s0, b21 = (bih2[r1] + bhh2[r1]) * s1;

    DECL6(u0a); DECL6(u0b);
    DECL6(v1a); DECL6(v1b); DECL6(u1a); DECL6(u1b);
    DECL6(v2a); DECL6(v2b); DECL6(u2a); DECL6(u2b);
    LOAD6(u0a, Whh0, r0, s0); LOAD6(u0b, Whh0, r1, s1);
    LOAD6(v1a, Wih1, r0, s0); LOAD6(v1b, Wih1, r1, s1);
    LOAD6(u1a, Whh1, r0, s0); LOAD6(u1b, Whh1, r1, s1);
    LOAD6(v2a, Wih2, r0, s0); LOAD6(v2b, Wih2, r1, s1);
    LOAD6(u2a, Whh2, r0, s0); LOAD6(u2b, Whh2, r1, s1);

    DECL6(h0); DECL6(h1); DECL6(h2);
    ZERO6(h0); ZERO6(h1); ZERO6(h2);
    float c0 = 0.f, c1 = 0.f, c2 = 0.f;

    // per-layer cell update + broadcast (p0 lanes compute harmless garbage
    // cell state; only p1's h is broadcast. c stays finite on p0: |c| grows
    // at most linearly, tanh_c(+-inf)=+-1, no NaN path).
#define CELLUP(z0v, z1v, cv, HP) {                                       \
        float a0 = frcp(1.0f + fexp2(z0v));      /* i (p0) / f (p1) */   \
        float rr = frcp(1.0f + fexp2(z1v));                              \
        float a1 = fmaf(A1, rr, B1);             /* g (p0) / o (p1) */   \
        float rcvd = swz<XCHG>(a0 * a1);         /* p1 receives i*g  */  \
        cv = fmaf(a0, cv, rcvd);                 /* p1: f*c + i*g    */  \
        float th = tanh_c(cv);                                           \
        float hh = a1 * th;                      /* p1: o*tanh(c)    */  \
        BCAST6(HP, hh); }

    // one skewed superstep: all dots first (read OLD h0/h1/h2), then the
    // three independent act/cell/bcast chains. Flags are compile-time.
#define SSTEP(XT, L0ON, L1ON, L2ON) do {                                 \
        float z00 = 0.f, z01 = 0.f, z10 = 0.f, z11 = 0.f,                \
              z20 = 0.f, z21 = 0.f;                                      \
        if (L2ON) { z20 = b20; z21 = b21;                                \
                    DOT6(z20, v2a, h1); DOT6(z21, v2b, h1);              \
                    DOT6(z20, u2a, h2); DOT6(z21, u2b, h2); }            \
        if (L1ON) { z10 = b10; z11 = b11;                                \
                    DOT6(z10, v1a, h0); DOT6(z11, v1b, h0);              \
                    DOT6(z10, u1a, h1); DOT6(z11, u1b, h1); }            \
        if (L0ON) { z00 = fmaf(wx0, (XT), b00);                          \
                    z01 = fmaf(wx1, (XT), b01);                          \
                    DOT6(z00, u0a, h0); DOT6(z01, u0b, h0); }            \
        if (L0ON) { CELLUP(z00, z01, c0, h0); }                          \
        if (L1ON) { CELLUP(z10, z11, c1, h1); }                          \
        if (L2ON) { CELLUP(z20, z21, c2, h2); }                          \
    } while (0)

    const float* xrow = x + (size_t)b * SEQT;
    const float2* xr2 = (const float2*)xrow;

    // prologue: tau=0 (L0), tau=1 (L0,L1)
    {
        float xa = xrow[0], xb = xrow[1];
        SSTEP(xa, true, false, false);
        SSTEP(xb, true, true, false);
    }
    // main: tau in [2, 510), 127 quads; x via 8B-aligned float2 pairs
    for (int i = 0; i < 127; ++i) {
        float2 qa = xr2[1 + 2 * i];
        float2 qb = xr2[2 + 2 * i];
        SSTEP(qa.x, true, true, true);
        SSTEP(qa.y, true, true, true);
        SSTEP(qb.x, true, true, true);
        SSTEP(qb.y, true, true, true);
    }
    // epilogue: tau=510,511 (all), tau=512 (L1,L2), tau=513 (L2)
    {
        float xa = xrow[510], xb = xrow[511];
        SSTEP(xa, true, true, true);
        SSTEP(xb, true, true, true);
        SSTEP(0.0f, false, true, true);
        SSTEP(0.0f, false, false, true);
    }

    // ---- final FC (h2 holds the broadcast final hidden state) ----
    if (sub == 0) {
        float o = fcb[0];
        o = fmaf(fcw[0], h20, o);
        o = fmaf(fcw[1], h21, o);
        o = fmaf(fcw[2], h22, o);
        o = fmaf(fcw[3], h23, o);
        o = fmaf(fcw[4], h24, o);
        o = fmaf(fcw[5], h25, o);
        out[b] = o;
    }
#undef SSTEP
#undef CELLUP
}

extern "C" void kernel_launch(void* const* d_in, const int* in_sizes, int n_in,
                              void* d_out, int out_size, void* d_ws, size_t ws_size,
                              hipStream_t stream) {
    const float* x    = (const float*)d_in[0];
    const float* Wih0 = (const float*)d_in[1];
    const float* Whh0 = (const float*)d_in[2];
    const float* bih0 = (const float*)d_in[3];
    const float* bhh0 = (const float*)d_in[4];
    const float* Wih1 = (const float*)d_in[5];
    const float* Whh1 = (const float*)d_in[6];
    const float* bih1 = (const float*)d_in[7];
    const float* bhh1 = (const float*)d_in[8];
    const float* Wih2 = (const float*)d_in[9];
    const float* Whh2 = (const float*)d_in[10];
    const float* bih2 = (const float*)d_in[11];
    const float* bhh2 = (const float*)d_in[12];
    const float* fcw  = (const float*)d_in[13];
    const float* fcb  = (const float*)d_in[14];
    float* out = (float*)d_out;

    const int B = out_size;            // 8192
    const int threads = B * 16;        // 16 lanes per batch element
    const int block = 256;
    const int grid = threads / block;  // 512 blocks -> 2 waves/SIMD
    lstm3_kernel<<<grid, block, 0, stream>>>(
        x, Wih0, Whh0, bih0, bhh0, Wih1, Whh1, bih1, bhh1,
        Wih2, Whh2, bih2, bhh2, fcw, fcb, out);
}